// Round 2
// baseline (565.511 us; speedup 1.0000x reference)
//
#include <hip/hip_runtime.h>
#include <math.h>

#define OUT 7
#define NVOX 343      // 7*7*7
#define LDSF 8192     // floats staged per channel (32 KB)
#define CPG 8         // channels per block
#define BLK 384       // 343 voxels + staging helpers; 6 waves

__device__ __forceinline__ void axis_samp(float c, float fdim, int dim,
                                          int& lo, int& hi, float& w0, float& w1) {
    float valid = (c > -1.0f && c < fdim) ? 1.0f : 0.0f;
    float cc = fminf(fmaxf(c, 0.0f), fdim - 1.0f);
    lo = (int)floorf(cc);
    hi = min(lo + 1, dim - 1);
    float fr = cc - (float)lo;
    w0 = (1.0f - fr) * valid;
    w1 = fr * valid;
}

__global__ __launch_bounds__(BLK) void roi_align_ms3d_lds_kernel(
    const float* __restrict__ f0, const float* __restrict__ f1,
    const float* __restrict__ f2, const float* __restrict__ f3,
    const float* __restrict__ boxes, float* __restrict__ out,
    int N, int C, int d0, int d1, int d2_, int d3)
{
    __shared__ float lds[LDSF];

    const int n = blockIdx.y;
    const int g = blockIdx.x;          // channel group
    const int tid = threadIdx.x;

    const float* bp = boxes + n * 6;
    float b0 = bp[0], b1 = bp[1], b2 = bp[2];
    float b3 = bp[3], b4 = bp[4], b5 = bp[5];

    // level_map
    float vol = (b3 - b0) * (b4 - b1) * (b5 - b2);
    float s = cbrtf(vol);
    float lvl = floorf(4.0f + log2f(s / 160.0f) + 1e-6f);
    lvl = fminf(fmaxf(lvl, 2.0f), 5.0f);
    int l = (int)lvl - 2;

    const float* f;
    int dim;
    float scale;
    if (l == 0)      { f = f0; dim = d0;  scale = 0.25f;    }
    else if (l == 1) { f = f1; dim = d1;  scale = 0.125f;   }
    else if (l == 2) { f = f2; dim = d2_; scale = 0.0625f;  }
    else             { f = f3; dim = d3;  scale = 0.03125f; }

    const float fdim = (float)dim;
    const int dsq = dim * dim;
    const size_t dcube = (size_t)dim * dsq;

    float sx = b0 * scale, sy = b1 * scale, sz = b2 * scale;
    float szx = fmaxf(b3 * scale - sx, 1.0f);
    float szy = fmaxf(b4 * scale - sy, 1.0f);
    float szz = fmaxf(b5 * scale - sz, 1.0f);
    float bx = szx * (1.0f / OUT), by = szy * (1.0f / OUT), bz = szz * (1.0f / OUT);

    // Region of lattice points touched by any sub-sample (after clipping):
    // sample coords span [start + 0.25*b, start + 6.75*b]
    int x0 = (int)floorf(fminf(fmaxf(sx + 0.25f * bx, 0.0f), fdim - 1.0f));
    int x1 = min((int)floorf(fminf(fmaxf(sx + 6.75f * bx, 0.0f), fdim - 1.0f)) + 1, dim - 1);
    int y0 = (int)floorf(fminf(fmaxf(sy + 0.25f * by, 0.0f), fdim - 1.0f));
    int y1 = min((int)floorf(fminf(fmaxf(sy + 6.75f * by, 0.0f), fdim - 1.0f)) + 1, dim - 1);
    int z0 = (int)floorf(fminf(fmaxf(sz + 0.25f * bz, 0.0f), fdim - 1.0f));
    int z1 = min((int)floorf(fminf(fmaxf(sz + 6.75f * bz, 0.0f), fdim - 1.0f)) + 1, dim - 1);

    int nx = x1 - x0 + 1, ny = y1 - y0 + 1, nz = z1 - z0 + 1;
    int nrows = nx * ny;
    int nreg = nrows * nz;

    // Per-voxel axis sampling data (computed once, reused over CPG channels)
    int xl[2], xh[2], yl[2], yh[2], zl[2], zh[2];
    float xw0[2], xw1[2], yw0[2], yw1[2], zw0[2], zw1[2];
    int ox = 0, oy = 0, oz = 0;
    if (tid < NVOX) {
        oz = tid % OUT;
        oy = (tid / OUT) % OUT;
        ox = tid / (OUT * OUT);
        #pragma unroll
        for (int r = 0; r < 2; ++r) {
            float off = 0.25f + 0.5f * (float)r;
            axis_samp(sx + ((float)ox + off) * bx, fdim, dim, xl[r], xh[r], xw0[r], xw1[r]);
            axis_samp(sy + ((float)oy + off) * by, fdim, dim, yl[r], yh[r], yw0[r], yw1[r]);
            axis_samp(sz + ((float)oz + off) * bz, fdim, dim, zl[r], zh[r], zw0[r], zw1[r]);
        }
    }

    if (nreg <= LDSF) {
        // ---------- LDS staging path (block-uniform branch) ----------
        int XL[2], XH[2], YL[2], YH[2], ZL[2], ZH[2];
        int nynz = ny * nz;
        if (tid < NVOX) {
            #pragma unroll
            for (int r = 0; r < 2; ++r) {
                XL[r] = (xl[r] - x0) * nynz;
                XH[r] = (xh[r] - x0) * nynz;
                YL[r] = (yl[r] - y0) * nz;
                YH[r] = (yh[r] - y0) * nz;
                ZL[r] = zl[r] - z0;
                ZH[r] = zh[r] - z0;
            }
        }

        const int col = tid & 15;
        const int row0 = tid >> 4;

        for (int ci = 0; ci < CPG; ++ci) {
            int ch = g * CPG + ci;
            const float* fc = f + (size_t)ch * dcube;

            // stage region: 16 lanes per row, rows strided by BLK/16
            for (int row = row0; row < nrows; row += (BLK / 16)) {
                int rx = row / ny;
                int ry = row - rx * ny;
                const float* src = fc + ((size_t)(x0 + rx) * dim + (y0 + ry)) * dim + z0;
                float* dst = lds + row * nz;
                for (int cc = col; cc < nz; cc += 16) dst[cc] = src[cc];
            }
            __syncthreads();

            if (tid < NVOX) {
                float acc = 0.0f;
                #pragma unroll
                for (int rx2 = 0; rx2 < 2; ++rx2) {
                    #pragma unroll
                    for (int ry2 = 0; ry2 < 2; ++ry2) {
                        #pragma unroll
                        for (int rz2 = 0; rz2 < 2; ++rz2) {
                            int bXL = XL[rx2], bXH = XH[rx2];
                            int bYL = YL[ry2], bYH = YH[ry2];
                            int bZL = ZL[rz2], bZH = ZH[rz2];
                            float v000 = lds[bXL + bYL + bZL];
                            float v001 = lds[bXL + bYL + bZH];
                            float v010 = lds[bXL + bYH + bZL];
                            float v011 = lds[bXL + bYH + bZH];
                            float v100 = lds[bXH + bYL + bZL];
                            float v101 = lds[bXH + bYL + bZH];
                            float v110 = lds[bXH + bYH + bZL];
                            float v111 = lds[bXH + bYH + bZH];
                            float wz0 = zw0[rz2], wz1 = zw1[rz2];
                            float vx0 = yw0[ry2] * (wz0 * v000 + wz1 * v001)
                                      + yw1[ry2] * (wz0 * v010 + wz1 * v011);
                            float vx1 = yw0[ry2] * (wz0 * v100 + wz1 * v101)
                                      + yw1[ry2] * (wz0 * v110 + wz1 * v111);
                            acc += xw0[rx2] * vx0 + xw1[rx2] * vx1;
                        }
                    }
                }
                out[((size_t)n * C + ch) * NVOX + tid] = acc * 0.125f;
            }
            __syncthreads();
        }
    } else {
        // ---------- fallback: direct global loads (rare oversized regions) ----------
        if (tid < NVOX) {
            int XL[2], XH[2], YL[2], YH[2], ZL[2], ZH[2];
            #pragma unroll
            for (int r = 0; r < 2; ++r) {
                XL[r] = xl[r] * dsq;
                XH[r] = xh[r] * dsq;
                YL[r] = yl[r] * dim;
                YH[r] = yh[r] * dim;
                ZL[r] = zl[r];
                ZH[r] = zh[r];
            }
            for (int ci = 0; ci < CPG; ++ci) {
                int ch = g * CPG + ci;
                const float* fc = f + (size_t)ch * dcube;
                float acc = 0.0f;
                #pragma unroll
                for (int rx2 = 0; rx2 < 2; ++rx2) {
                    #pragma unroll
                    for (int ry2 = 0; ry2 < 2; ++ry2) {
                        #pragma unroll
                        for (int rz2 = 0; rz2 < 2; ++rz2) {
                            int bXL = XL[rx2], bXH = XH[rx2];
                            int bYL = YL[ry2], bYH = YH[ry2];
                            int bZL = ZL[rz2], bZH = ZH[rz2];
                            float v000 = fc[bXL + bYL + bZL];
                            float v001 = fc[bXL + bYL + bZH];
                            float v010 = fc[bXL + bYH + bZL];
                            float v011 = fc[bXL + bYH + bZH];
                            float v100 = fc[bXH + bYL + bZL];
                            float v101 = fc[bXH + bYL + bZH];
                            float v110 = fc[bXH + bYH + bZL];
                            float v111 = fc[bXH + bYH + bZH];
                            float wz0 = zw0[rz2], wz1 = zw1[rz2];
                            float vx0 = yw0[ry2] * (wz0 * v000 + wz1 * v001)
                                      + yw1[ry2] * (wz0 * v010 + wz1 * v011);
                            float vx1 = yw0[ry2] * (wz0 * v100 + wz1 * v101)
                                      + yw1[ry2] * (wz0 * v110 + wz1 * v111);
                            acc += xw0[rx2] * vx0 + xw1[rx2] * vx1;
                        }
                    }
                }
                out[((size_t)n * C + ch) * NVOX + tid] = acc * 0.125f;
            }
        }
    }
}

extern "C" void kernel_launch(void* const* d_in, const int* in_sizes, int n_in,
                              void* d_out, int out_size, void* d_ws, size_t ws_size,
                              hipStream_t stream) {
    const float* f0 = (const float*)d_in[0];
    const float* f1 = (const float*)d_in[1];
    const float* f2 = (const float*)d_in[2];
    const float* f3 = (const float*)d_in[3];
    const float* boxes = (const float*)d_in[4];
    float* out = (float*)d_out;

    int N = in_sizes[4] / 6;
    int C = out_size / (N * NVOX);

    auto cdim = [&](int sz) {
        int per_c = sz / C;
        return (int)(cbrtf((float)per_c) + 0.5f);
    };
    int d0 = cdim(in_sizes[0]);
    int d1 = cdim(in_sizes[1]);
    int d2 = cdim(in_sizes[2]);
    int d3 = cdim(in_sizes[3]);

    int ngrp = C / CPG;  // 8 channel-groups of 8
    dim3 grid(ngrp, N);
    roi_align_ms3d_lds_kernel<<<grid, BLK, 0, stream>>>(f0, f1, f2, f3, boxes, out,
                                                        N, C, d0, d1, d2, d3);
}

// Round 3
// 298.372 us; speedup vs baseline: 1.8953x; 1.8953x over previous
//
#include <hip/hip_runtime.h>
#include <math.h>

#define OUT 7
#define NVOX 343      // 7*7*7
#define LDSF 7680     // floats staged per block (30 KB) -> 5 blocks/CU
#define BLK 384       // 6 waves

__device__ __forceinline__ void axis_samp(float c, float fdim, int dim,
                                          int& lo, int& hi, float& w0, float& w1) {
    float valid = (c > -1.0f && c < fdim) ? 1.0f : 0.0f;
    float cc = fminf(fmaxf(c, 0.0f), fdim - 1.0f);
    lo = (int)floorf(cc);
    hi = min(lo + 1, dim - 1);
    float fr = cc - (float)lo;
    w0 = (1.0f - fr) * valid;
    w1 = fr * valid;
}

__global__ __launch_bounds__(BLK) void roi_align_ms3d_kernel(
    const float* __restrict__ f0, const float* __restrict__ f1,
    const float* __restrict__ f2, const float* __restrict__ f3,
    const float* __restrict__ boxes, float* __restrict__ out,
    int N, int C, int d0, int d1, int d2_, int d3)
{
    __shared__ float lds[LDSF];

    const int c   = blockIdx.x;   // channel
    const int n   = blockIdx.y;   // box
    const int tid = threadIdx.x;

    const float* bp = boxes + n * 6;
    float b0 = bp[0], b1 = bp[1], b2 = bp[2];
    float b3 = bp[3], b4 = bp[4], b5 = bp[5];

    // level_map
    float vol = (b3 - b0) * (b4 - b1) * (b5 - b2);
    float s = cbrtf(vol);
    float lvl = floorf(4.0f + log2f(s / 160.0f) + 1e-6f);
    lvl = fminf(fmaxf(lvl, 2.0f), 5.0f);
    int l = (int)lvl - 2;

    const float* f;
    int dim;
    float scale;
    if (l == 0)      { f = f0; dim = d0;  scale = 0.25f;    }
    else if (l == 1) { f = f1; dim = d1;  scale = 0.125f;   }
    else if (l == 2) { f = f2; dim = d2_; scale = 0.0625f;  }
    else             { f = f3; dim = d3;  scale = 0.03125f; }

    const float fdim = (float)dim;
    const int dsq = dim * dim;
    const size_t dcube = (size_t)dim * dsq;
    const float* fc = f + (size_t)c * dcube;

    float sx = b0 * scale, sy = b1 * scale, sz = b2 * scale;
    float szx = fmaxf(b3 * scale - sx, 1.0f);
    float szy = fmaxf(b4 * scale - sy, 1.0f);
    float szz = fmaxf(b5 * scale - sz, 1.0f);
    float bx = szx * (1.0f / OUT), by = szy * (1.0f / OUT), bz = szz * (1.0f / OUT);

    // Lattice region touched by any clipped sub-sample:
    // sample coords span [start + 0.25*b, start + 6.75*b]
    int x0 = (int)floorf(fminf(fmaxf(sx + 0.25f * bx, 0.0f), fdim - 1.0f));
    int x1 = min((int)floorf(fminf(fmaxf(sx + 6.75f * bx, 0.0f), fdim - 1.0f)) + 1, dim - 1);
    int y0 = (int)floorf(fminf(fmaxf(sy + 0.25f * by, 0.0f), fdim - 1.0f));
    int y1 = min((int)floorf(fminf(fmaxf(sy + 6.75f * by, 0.0f), fdim - 1.0f)) + 1, dim - 1);
    int z0 = (int)floorf(fminf(fmaxf(sz + 0.25f * bz, 0.0f), fdim - 1.0f));
    int z1 = min((int)floorf(fminf(fmaxf(sz + 6.75f * bz, 0.0f), fdim - 1.0f)) + 1, dim - 1);

    int nx = x1 - x0 + 1, ny = y1 - y0 + 1, nz = z1 - z0 + 1;
    int nynz = ny * nz;
    int nreg = nx * nynz;

    // Per-voxel axis data (one voxel per thread; tid >= NVOX only stages)
    int ox = 0, oy = 0, oz = 0;
    int xl[2], xh[2], yl[2], yh[2], zl[2], zh[2];
    float xw0[2], xw1[2], yw0[2], yw1[2], zw0[2], zw1[2];
    if (tid < NVOX) {
        oz = tid % OUT;
        oy = (tid / OUT) % OUT;
        ox = tid / (OUT * OUT);
        #pragma unroll
        for (int r = 0; r < 2; ++r) {
            float off = 0.25f + 0.5f * (float)r;
            axis_samp(sx + ((float)ox + off) * bx, fdim, dim, xl[r], xh[r], xw0[r], xw1[r]);
            axis_samp(sy + ((float)oy + off) * by, fdim, dim, yl[r], yh[r], yw0[r], yw1[r]);
            axis_samp(sz + ((float)oz + off) * bz, fdim, dim, zl[r], zh[r], zw0[r], zw1[r]);
        }
    }

    if (nreg <= LDSF) {
        // ---- stage region once (coalesced, z-fastest), one barrier ----
        for (int e = tid; e < nreg; e += BLK) {
            int row = e / nz;
            int zz = e - row * nz;
            int rx = row / ny;
            int ry = row - rx * ny;
            lds[e] = fc[((size_t)(x0 + rx) * dim + (y0 + ry)) * dim + (z0 + zz)];
        }
        __syncthreads();

        if (tid < NVOX) {
            int XL[2], XH[2], YL[2], YH[2], ZL[2], ZH[2];
            #pragma unroll
            for (int r = 0; r < 2; ++r) {
                XL[r] = (xl[r] - x0) * nynz;
                XH[r] = (xh[r] - x0) * nynz;
                YL[r] = (yl[r] - y0) * nz;
                YH[r] = (yh[r] - y0) * nz;
                ZL[r] = zl[r] - z0;
                ZH[r] = zh[r] - z0;
            }
            float acc = 0.0f;
            #pragma unroll
            for (int rx2 = 0; rx2 < 2; ++rx2) {
                #pragma unroll
                for (int ry2 = 0; ry2 < 2; ++ry2) {
                    #pragma unroll
                    for (int rz2 = 0; rz2 < 2; ++rz2) {
                        int bXL = XL[rx2], bXH = XH[rx2];
                        int bYL = YL[ry2], bYH = YH[ry2];
                        int bZL = ZL[rz2], bZH = ZH[rz2];
                        float v000 = lds[bXL + bYL + bZL];
                        float v001 = lds[bXL + bYL + bZH];
                        float v010 = lds[bXL + bYH + bZL];
                        float v011 = lds[bXL + bYH + bZH];
                        float v100 = lds[bXH + bYL + bZL];
                        float v101 = lds[bXH + bYL + bZH];
                        float v110 = lds[bXH + bYH + bZL];
                        float v111 = lds[bXH + bYH + bZH];
                        float wz0 = zw0[rz2], wz1 = zw1[rz2];
                        float vx0 = yw0[ry2] * (wz0 * v000 + wz1 * v001)
                                  + yw1[ry2] * (wz0 * v010 + wz1 * v011);
                        float vx1 = yw0[ry2] * (wz0 * v100 + wz1 * v101)
                                  + yw1[ry2] * (wz0 * v110 + wz1 * v111);
                        acc += xw0[rx2] * vx0 + xw1[rx2] * vx1;
                    }
                }
            }
            out[((size_t)n * C + c) * NVOX + tid] = acc * 0.125f;
        }
    } else {
        // ---- rare oversized region: direct global loads ----
        if (tid < NVOX) {
            float acc = 0.0f;
            #pragma unroll
            for (int rx2 = 0; rx2 < 2; ++rx2) {
                const float* pxl = fc + (size_t)xl[rx2] * dsq;
                const float* pxh = fc + (size_t)xh[rx2] * dsq;
                float wx0 = xw0[rx2], wx1 = xw1[rx2];
                #pragma unroll
                for (int ry2 = 0; ry2 < 2; ++ry2) {
                    int ryl = yl[ry2] * dim;
                    int ryh = yh[ry2] * dim;
                    float wy0 = yw0[ry2], wy1 = yw1[ry2];
                    #pragma unroll
                    for (int rz2 = 0; rz2 < 2; ++rz2) {
                        int bZL = zl[rz2], bZH = zh[rz2];
                        float wz0 = zw0[rz2], wz1 = zw1[rz2];
                        float v000 = pxl[ryl + bZL];
                        float v001 = pxl[ryl + bZH];
                        float v010 = pxl[ryh + bZL];
                        float v011 = pxl[ryh + bZH];
                        float v100 = pxh[ryl + bZL];
                        float v101 = pxh[ryl + bZH];
                        float v110 = pxh[ryh + bZL];
                        float v111 = pxh[ryh + bZH];
                        float vx0 = wy0 * (wz0 * v000 + wz1 * v001)
                                  + wy1 * (wz0 * v010 + wz1 * v011);
                        float vx1 = wy0 * (wz0 * v100 + wz1 * v101)
                                  + wy1 * (wz0 * v110 + wz1 * v111);
                        acc += wx0 * vx0 + wx1 * vx1;
                    }
                }
            }
            out[((size_t)n * C + c) * NVOX + tid] = acc * 0.125f;
        }
    }
}

extern "C" void kernel_launch(void* const* d_in, const int* in_sizes, int n_in,
                              void* d_out, int out_size, void* d_ws, size_t ws_size,
                              hipStream_t stream) {
    const float* f0 = (const float*)d_in[0];
    const float* f1 = (const float*)d_in[1];
    const float* f2 = (const float*)d_in[2];
    const float* f3 = (const float*)d_in[3];
    const float* boxes = (const float*)d_in[4];
    float* out = (float*)d_out;

    int N = in_sizes[4] / 6;
    int C = out_size / (N * NVOX);

    auto cdim = [&](int sz) {
        int per_c = sz / C;
        return (int)(cbrtf((float)per_c) + 0.5f);
    };
    int d0 = cdim(in_sizes[0]);
    int d1 = cdim(in_sizes[1]);
    int d2 = cdim(in_sizes[2]);
    int d3 = cdim(in_sizes[3]);

    dim3 grid(C, N);   // one block per (box, channel)
    roi_align_ms3d_kernel<<<grid, BLK, 0, stream>>>(f0, f1, f2, f3, boxes, out,
                                                    N, C, d0, d1, d2, d3);
}

// Round 4
// 279.518 us; speedup vs baseline: 2.0232x; 1.0674x over previous
//
#include <hip/hip_runtime.h>
#include <math.h>

#define OUT 7
#define NVOX 343        // 7*7*7
#define LDSF 11776      // floats staged per block (46 KB) -> 3 blocks/CU
#define BLK 512         // 8 waves

__device__ __forceinline__ void axis_samp(float c, float fdim, int dim,
                                          int& lo, float& w0, float& w1) {
    float valid = (c > -1.0f && c < fdim) ? 1.0f : 0.0f;
    float cc = fminf(fmaxf(c, 0.0f), fdim - 1.0f);
    lo = (int)floorf(cc);
    float fr = cc - (float)lo;
    w0 = (1.0f - fr) * valid;
    w1 = fr * valid;     // == 0 whenever hi would be clamped (fr==0 at lo==dim-1)
}

__global__ __launch_bounds__(BLK) void roi_align_ms3d_kernel(
    const float* __restrict__ f0, const float* __restrict__ f1,
    const float* __restrict__ f2, const float* __restrict__ f3,
    const float* __restrict__ boxes, float* __restrict__ out,
    int N, int C, int d0, int d1, int d2_, int d3)
{
    __shared__ float lds[LDSF];

    const int c   = blockIdx.x;   // channel
    const int n   = blockIdx.y;   // box
    const int tid = threadIdx.x;

    const float* bp = boxes + n * 6;
    float b0 = bp[0], b1 = bp[1], b2 = bp[2];
    float b3 = bp[3], b4 = bp[4], b5 = bp[5];

    // level_map
    float vol = (b3 - b0) * (b4 - b1) * (b5 - b2);
    float s = cbrtf(vol);
    float lvl = floorf(4.0f + log2f(s / 160.0f) + 1e-6f);
    lvl = fminf(fmaxf(lvl, 2.0f), 5.0f);
    int l = (int)lvl - 2;

    const float* f;
    int dim;
    float scale;
    if (l == 0)      { f = f0; dim = d0;  scale = 0.25f;    }
    else if (l == 1) { f = f1; dim = d1;  scale = 0.125f;   }
    else if (l == 2) { f = f2; dim = d2_; scale = 0.0625f;  }
    else             { f = f3; dim = d3;  scale = 0.03125f; }

    const float fdim = (float)dim;
    const int dsq = dim * dim;
    const size_t dcube = (size_t)dim * dsq;
    const float* fc = f + (size_t)c * dcube;

    float sx = b0 * scale, sy = b1 * scale, sz = b2 * scale;
    float szx = fmaxf(b3 * scale - sx, 1.0f);
    float szy = fmaxf(b4 * scale - sy, 1.0f);
    float szz = fmaxf(b5 * scale - sz, 1.0f);
    float bx = szx * (1.0f / OUT), by = szy * (1.0f / OUT), bz = szz * (1.0f / OUT);

    // Lattice region touched by any clipped sub-sample:
    // sample coords span [start + 0.25*b, start + 6.75*b]
    int x0 = (int)floorf(fminf(fmaxf(sx + 0.25f * bx, 0.0f), fdim - 1.0f));
    int x1 = min((int)floorf(fminf(fmaxf(sx + 6.75f * bx, 0.0f), fdim - 1.0f)) + 1, dim - 1);
    int y0 = (int)floorf(fminf(fmaxf(sy + 0.25f * by, 0.0f), fdim - 1.0f));
    int y1 = min((int)floorf(fminf(fmaxf(sy + 6.75f * by, 0.0f), fdim - 1.0f)) + 1, dim - 1);
    int z0 = (int)floorf(fminf(fmaxf(sz + 0.25f * bz, 0.0f), fdim - 1.0f));
    int z1 = min((int)floorf(fminf(fmaxf(sz + 6.75f * bz, 0.0f), fdim - 1.0f)) + 1, dim - 1);

    int nx = x1 - x0 + 1, ny = y1 - y0 + 1, nz = z1 - z0 + 1;
    int nzp = nz + 1;                 // +1 z-pad so (lo, lo+1) is always readable
    int nynzp = ny * nzp;
    int nrows = nx * ny;
    int nregp = nrows * nzp;

    // Per-voxel axis data (one voxel per thread; tid >= NVOX only stages)
    int xl[2], yl[2], zl[2];
    float xw0[2], xw1[2], yw0[2], yw1[2], zw0[2], zw1[2];
    if (tid < NVOX) {
        int oz = tid % OUT;
        int oy = (tid / OUT) % OUT;
        int ox = tid / (OUT * OUT);
        #pragma unroll
        for (int r = 0; r < 2; ++r) {
            float off = 0.25f + 0.5f * (float)r;
            axis_samp(sx + ((float)ox + off) * bx, fdim, dim, xl[r], xw0[r], xw1[r]);
            axis_samp(sy + ((float)oy + off) * by, fdim, dim, yl[r], yw0[r], yw1[r]);
            axis_samp(sz + ((float)oz + off) * bz, fdim, dim, zl[r], zw0[r], zw1[r]);
        }
    }

    if (nregp <= LDSF) {
        // ---- stage padded region once (flat index, rcp-based decompose) ----
        float rnzp = 1.0f / (float)nzp;
        float rny  = 1.0f / (float)ny;
        for (int e = tid; e < nregp; e += BLK) {
            // row = e / nzp; zz = e % nzp  (float-rcp with +/-1 correction)
            int row = (int)((float)e * rnzp);
            int zz = e - row * nzp;
            if (zz < 0)        { row -= 1; zz += nzp; }
            else if (zz >= nzp){ row += 1; zz -= nzp; }
            // rx = row / ny; ry = row % ny
            int rx = (int)((float)row * rny);
            int ry = row - rx * ny;
            if (ry < 0)        { rx -= 1; ry += ny; }
            else if (ry >= ny) { rx += 1; ry -= ny; }
            int zsrc = min(zz, nz - 1);   // pad slot duplicates last z (finite; weight 0)
            lds[e] = fc[((size_t)(x0 + rx) * dim + (y0 + ry)) * dim + (z0 + zsrc)];
        }
        __syncthreads();

        if (tid < NVOX) {
            int XL[2], XH[2], YL[2], YH[2], ZL[2];
            #pragma unroll
            for (int r = 0; r < 2; ++r) {
                int xlr = xl[r] - x0;
                int xhr = min(xl[r] + 1, dim - 1) - x0;
                int ylr = yl[r] - y0;
                int yhr = min(yl[r] + 1, dim - 1) - y0;
                XL[r] = xlr * nynzp;
                XH[r] = xhr * nynzp;
                YL[r] = ylr * nzp;
                YH[r] = yhr * nzp;
                ZL[r] = zl[r] - z0;
            }
            float acc = 0.0f;
            #pragma unroll
            for (int rx2 = 0; rx2 < 2; ++rx2) {
                #pragma unroll
                for (int ry2 = 0; ry2 < 2; ++ry2) {
                    #pragma unroll
                    for (int rz2 = 0; rz2 < 2; ++rz2) {
                        // 4 base pointers; each reads adjacent z pair (ds_read2)
                        const float* pll = lds + (XL[rx2] + YL[ry2] + ZL[rz2]);
                        const float* plh = lds + (XL[rx2] + YH[ry2] + ZL[rz2]);
                        const float* phl = lds + (XH[rx2] + YL[ry2] + ZL[rz2]);
                        const float* phh = lds + (XH[rx2] + YH[ry2] + ZL[rz2]);
                        float v000 = pll[0], v001 = pll[1];
                        float v010 = plh[0], v011 = plh[1];
                        float v100 = phl[0], v101 = phl[1];
                        float v110 = phh[0], v111 = phh[1];
                        float wz0 = zw0[rz2], wz1 = zw1[rz2];
                        float vx0 = yw0[ry2] * (wz0 * v000 + wz1 * v001)
                                  + yw1[ry2] * (wz0 * v010 + wz1 * v011);
                        float vx1 = yw0[ry2] * (wz0 * v100 + wz1 * v101)
                                  + yw1[ry2] * (wz0 * v110 + wz1 * v111);
                        acc += xw0[rx2] * vx0 + xw1[rx2] * vx1;
                    }
                }
            }
            out[((size_t)n * C + c) * NVOX + tid] = acc * 0.125f;
        }
    } else {
        // ---- safety net (should be ~never hit): direct global loads ----
        if (tid < NVOX) {
            float acc = 0.0f;
            #pragma unroll
            for (int rx2 = 0; rx2 < 2; ++rx2) {
                const float* pxl = fc + (size_t)xl[rx2] * dsq;
                const float* pxh = fc + (size_t)min(xl[rx2] + 1, dim - 1) * dsq;
                float wx0 = xw0[rx2], wx1 = xw1[rx2];
                #pragma unroll
                for (int ry2 = 0; ry2 < 2; ++ry2) {
                    int ryl = yl[ry2] * dim;
                    int ryh = min(yl[ry2] + 1, dim - 1) * dim;
                    float wy0 = yw0[ry2], wy1 = yw1[ry2];
                    #pragma unroll
                    for (int rz2 = 0; rz2 < 2; ++rz2) {
                        int bZL = zl[rz2];
                        int bZH = min(zl[rz2] + 1, dim - 1);
                        float wz0 = zw0[rz2], wz1 = zw1[rz2];
                        float v000 = pxl[ryl + bZL];
                        float v001 = pxl[ryl + bZH];
                        float v010 = pxl[ryh + bZL];
                        float v011 = pxl[ryh + bZH];
                        float v100 = pxh[ryl + bZL];
                        float v101 = pxh[ryl + bZH];
                        float v110 = pxh[ryh + bZL];
                        float v111 = pxh[ryh + bZH];
                        float vx0 = wy0 * (wz0 * v000 + wz1 * v001)
                                  + wy1 * (wz0 * v010 + wz1 * v011);
                        float vx1 = wy0 * (wz0 * v100 + wz1 * v101)
                                  + wy1 * (wz0 * v110 + wz1 * v111);
                        acc += wx0 * vx0 + wx1 * vx1;
                    }
                }
            }
            out[((size_t)n * C + c) * NVOX + tid] = acc * 0.125f;
        }
    }
}

extern "C" void kernel_launch(void* const* d_in, const int* in_sizes, int n_in,
                              void* d_out, int out_size, void* d_ws, size_t ws_size,
                              hipStream_t stream) {
    const float* f0 = (const float*)d_in[0];
    const float* f1 = (const float*)d_in[1];
    const float* f2 = (const float*)d_in[2];
    const float* f3 = (const float*)d_in[3];
    const float* boxes = (const float*)d_in[4];
    float* out = (float*)d_out;

    int N = in_sizes[4] / 6;
    int C = out_size / (N * NVOX);

    auto cdim = [&](int sz) {
        int per_c = sz / C;
        return (int)(cbrtf((float)per_c) + 0.5f);
    };
    int d0 = cdim(in_sizes[0]);
    int d1 = cdim(in_sizes[1]);
    int d2 = cdim(in_sizes[2]);
    int d3 = cdim(in_sizes[3]);

    dim3 grid(C, N);   // one block per (box, channel)
    roi_align_ms3d_kernel<<<grid, BLK, 0, stream>>>(f0, f1, f2, f3, boxes, out,
                                                    N, C, d0, d1, d2, d3);
}